// Round 11
// baseline (818.973 us; speedup 1.0000x reference)
//
#include <hip/hip_runtime.h>

// TreeLstmDecoder: B=64 trees, K=4, D=6, V=600, L=256, N_PER=1365, N=87360.
// 15-launch schedule. NEW in this round: sibling LSTM fused into the sibdual
// GEMM epilogue via GATE-INTERLEAVED B layout (col c' = unit*4+gate): the 4
// gates of a (row,unit) land in 4 adjacent lanes of the MFMA C-layout; 3
// shfl_xor collect them, lane gid==0 computes cn/hn and writes h/c directly.
// GATES buffer and the two 21888-block sibling-LSTM launches are eliminated;
// gates are consumed in fp32 (more precise than the old bf16 round-trip).
//  L1  k_pack (incl. interleaved USWHHS gates, WIHST2, BS2)
//  L2  k_s0                   (21824 sibling s=0 states, LDS-free)
//  L3  zdual || sibdual1-FUSE [GEMM: HPRED roots+gatesP ; UPROJ1+fused LSTM]
//  L4  plstm0 (64)
//  L5  pdual1 || sibdual2-FUSE
//  L6  plstm1 (256)
//  L7  pdual2 || sibdual3     [PPA d2+gatesP ; UPROJ3 only]
//  L8  plstm2   L9 pdual3   L10 plstm3   L11 pdual4
//  L12 plstm4 || assembleA (chain rows 0..5440)
//  L13 pdual5 (PPA d5)
//  L14 assembleB (chain rows 5440..21824)
//  L15 k_mm_tail (87360x602x256 GEMM + log-softmax, register-resident)
// All GEMMs: C = A*B^T, bf16 operands, fp32 MFMA accumulate. Plain stores
// (R6: nontemporal breaks L2 write-combining on 4B scattered stores).

typedef unsigned short u16;
typedef short bf16x8 __attribute__((ext_vector_type(8)));
typedef float f32x4 __attribute__((ext_vector_type(4)));

#define NPER 1365
#define VDIM 600
#define VD2  602

#define MODE_PPA   0
#define MODE_UPROJ 1
#define MODE_ROOT  2
#define MODE_FUSE  3   // UPROJ tiles + fused sibling LSTM on gate tiles

__device__ __forceinline__ float b2f(u16 h) {
  union { unsigned u; float f; } v; v.u = ((unsigned)h) << 16; return v.f;
}
__device__ __forceinline__ u16 f2bf(float f) {
  union { float f; unsigned u; } v; v.f = f;
  unsigned r = v.u + 0x7fff + ((v.u >> 16) & 1);
  return (u16)(r >> 16);
}
__device__ __forceinline__ float fsigm(float x) {
  return __fdividef(1.f, 1.f + __expf(-x));
}
__device__ __forceinline__ float ftanh(float x) {
  float e = __expf(-2.f * fabsf(x));
  float r = __fdividef(1.f - e, 1.f + e);
  return x < 0.f ? -r : r;
}

// chain-row ladder: r -> (off, pcs, start) for depths 1..5
__device__ __forceinline__ void ladder(int r, int& off, int& pcs, int& start) {
  if (r < 64)        { off = 0;    pcs = 0; start = 1;   }
  else if (r < 320)  { off = 64;   pcs = 2; start = 5;   }
  else if (r < 1344) { off = 320;  pcs = 4; start = 21;  }
  else if (r < 5440) { off = 1344; pcs = 6; start = 85;  }
  else               { off = 5440; pcs = 8; start = 341; }
}

// ---------------- pack kernel -----------------------------------------------
__global__ void k_pack(
    const float* __restrict__ Upar, const float* __restrict__ Whhp,
    const float* __restrict__ Usib, const float* __restrict__ Whhs,
    const float* __restrict__ z, const float* __restrict__ Wihp,
    const float* __restrict__ Wihs, const float* __restrict__ Wlab,
    const float* __restrict__ Wd, const float* __restrict__ Ww,
    const float* __restrict__ blab, const float* __restrict__ bd,
    const float* __restrict__ bw, const float* __restrict__ bihp,
    const float* __restrict__ bhhp, const float* __restrict__ bihs,
    const float* __restrict__ bhhs,
    u16* __restrict__ UPWHHP, u16* __restrict__ USWHHS, u16* __restrict__ ZBF,
    u16* __restrict__ WIHPT, u16* __restrict__ WIHST, u16* __restrict__ WEXT,
    float* __restrict__ BE, float* __restrict__ BP, float* __restrict__ BS,
    u16* __restrict__ WIHST2, float* __restrict__ BS2) {
  int i = blockIdx.x * 256 + threadIdx.x;
  if (i < 327680) {
    int r = i >> 8, c = i & 255;
    UPWHHP[i] = f2bf(r < 256 ? Upar[(r << 8) | c] : Whhp[((r - 256) << 8) | c]);
    return;
  }
  i -= 327680;
  if (i < 327680) {  // USWHHS: U rows plain; gate rows INTERLEAVED c'=unit*4+gate
    int r = i >> 8, c = i & 255;
    float v;
    if (r < 256) v = Usib[(r << 8) | c];
    else {
      int cp = r - 256, unit = cp >> 2, gate = cp & 3;
      v = Whhs[(size_t)(gate * 256 + unit) * 256 + c];
    }
    USWHHS[i] = f2bf(v);
    return;
  }
  i -= 327680;
  if (i < 16384) { ZBF[i] = f2bf(z[i]); return; }
  i -= 16384;
  if (i < 614400) {  // W_ih_p [1024,600] -> [600,1024]; coalesced writes
    int r = i >> 10, c = i & 1023;
    WIHPT[i] = f2bf(Wihp[c * VDIM + r]); return;
  }
  i -= 614400;
  if (i < 614400) {  // plain WIHST (used by k_s0)
    int r = i >> 10, c = i & 1023;
    WIHST[i] = f2bf(Wihs[c * VDIM + r]); return;
  }
  i -= 614400;
  if (i < VD2 * 256) {
    int r = i >> 8, c = i & 255;
    float v = (r < VDIM) ? Wlab[r * 256 + c] : ((r == VDIM) ? Wd[c] : Ww[c]);
    WEXT[i] = f2bf(v); return;
  }
  i -= VD2 * 256;
  if (i < VD2) { BE[i] = (i < VDIM) ? blab[i] : ((i == VDIM) ? bd[0] : bw[0]); return; }
  i -= VD2;
  if (i < 1024) { BP[i] = bihp[i] + bhhp[i]; return; }
  i -= 1024;
  if (i < 1024) { BS[i] = bihs[i] + bhhs[i]; return; }
  i -= 1024;
  if (i < 614400) {  // WIHST2: interleaved gx gather table
    int lab = i >> 10, cp = i & 1023;
    int unit = cp >> 2, gate = cp & 3;
    WIHST2[i] = f2bf(Wihs[(size_t)(gate * 256 + unit) * VDIM + lab]);
    return;
  }
  i -= 614400;
  if (i < 1024) {    // BS2: interleaved bias
    int unit = i >> 2, gate = i & 3;
    BS2[i] = bihs[gate * 256 + unit] + bhhs[gate * 256 + unit];
  }
}

// ---------------- dual GEMM device fn: C = A*B^T, B=[1280,256] concat -------
// n0>=256 tiles: MODE_FUSE -> fused sibling LSTM (gate-interleaved layout);
//                else gates[row*1024 + (col-256)] = bf16(acc).
// n0<256 tiles by mode:
//  MODE_PPA  : ppa[(ppoff+row)*256+col] = bf16(acc)
//  MODE_UPROJ/MODE_FUSE: uproj[row*256+col] = acc (fp32)
//  MODE_ROOT : hpred[row*NPER*256+col] = bf16(tanh(acc))  (root node rows)
__device__ __forceinline__ void dev_dual(
    int tile, int nx, const u16* __restrict__ A, const u16* __restrict__ B,
    int M, int mode, u16* __restrict__ ppa, int ppoff,
    float* __restrict__ uproj, u16* __restrict__ gates,
    u16* __restrict__ hpred,
    int kSib, const int* __restrict__ feat, const u16* __restrict__ wih2,
    const float* __restrict__ bs2, const u16* __restrict__ c_in,
    u16* __restrict__ h_out, u16* __restrict__ c_out) {
  static __shared__ __align__(16) u16 As[128 * 40];
  static __shared__ __align__(16) u16 Bs[128 * 40];
  const int m0 = (tile % nx) * 128, n0 = (tile / nx) * 128;
  const int tid = threadIdx.x;
  const int wave = tid >> 6, lane = tid & 63;
  const int quad = lane >> 4, lr = lane & 15;
  const int wm = (wave >> 1) * 64, wn = (wave & 1) * 64;
  const int srow = tid >> 2;
  const int sch = (tid & 3) << 3;

  f32x4 acc[4][4] = {};
  for (int t = 0; t < 8; ++t) {
    const int kk = t * 32;
    bf16x8 a0 = *(const bf16x8*)(A + (size_t)(m0 + srow) * 256 + kk + sch);
    bf16x8 a1 = *(const bf16x8*)(A + (size_t)(m0 + srow + 64) * 256 + kk + sch);
    bf16x8 b0 = *(const bf16x8*)(B + (size_t)(n0 + srow) * 256 + kk + sch);
    bf16x8 b1 = *(const bf16x8*)(B + (size_t)(n0 + srow + 64) * 256 + kk + sch);
    __syncthreads();
    *(bf16x8*)&As[srow * 40 + sch] = a0;
    *(bf16x8*)&As[(srow + 64) * 40 + sch] = a1;
    *(bf16x8*)&Bs[srow * 40 + sch] = b0;
    *(bf16x8*)&Bs[(srow + 64) * 40 + sch] = b1;
    __syncthreads();
    bf16x8 af[4], bfr[4];
#pragma unroll
    for (int tm = 0; tm < 4; ++tm)
      af[tm] = *(const bf16x8*)&As[(wm + tm * 16 + lr) * 40 + quad * 8];
#pragma unroll
    for (int tn = 0; tn < 4; ++tn)
      bfr[tn] = *(const bf16x8*)&Bs[(wn + tn * 16 + lr) * 40 + quad * 8];
#pragma unroll
    for (int tm = 0; tm < 4; ++tm)
#pragma unroll
      for (int tn = 0; tn < 4; ++tn)
        acc[tm][tn] = __builtin_amdgcn_mfma_f32_16x16x32_bf16(
            af[tm], bfr[tn], acc[tm][tn], 0, 0, 0);
  }

  const bool isg = (n0 >= 256);

  if (isg && mode == MODE_FUSE) {
    // Fused sibling LSTM. Gate-interleaved cols: c' = unit*4 + gate, so the
    // 4 gates of (row,unit) sit in 4 adjacent lanes (gid = lr&3 = gate; all
    // 16 lanes of a group share the same row -> shfl partners uniform).
#pragma unroll
    for (int tm = 0; tm < 4; ++tm) {
#pragma unroll
      for (int r = 0; r < 4; ++r) {
        int row = m0 + wm + tm * 16 + quad * 4 + r;
        if (row >= M) continue;
        int off, pcs, start; ladder(row, off, pcs, start);
        int lg = row - off;
        int t = lg >> pcs, j = lg & ((1 << pcs) - 1);
        int lab = feat[t * NPER + start + 4 * j + kSib];
        const u16* wr = wih2 + (size_t)lab * 1024;
#pragma unroll
        for (int tn = 0; tn < 4; ++tn) {
          int cp = (n0 - 256) + wn + tn * 16 + lr;
          float g = acc[tm][tn][r] + bs2[cp] + b2f(wr[cp]);
          int gid = lr & 3;
          float a = (gid == 2) ? ftanh(g) : fsigm(g);
          float x1 = __shfl_xor(a, 1, 64);   // gate^1
          float x2 = __shfl_xor(a, 2, 64);   // gate^2
          float x3 = __shfl_xor(x1, 2, 64);  // gate^3
          if (gid == 0) {                    // holds i; x1=f, x2=g, x3=o
            int unit = cp >> 2;
            float cv = b2f(c_in[(size_t)row * 256 + unit]);
            float cn = x1 * cv + a * x2;
            float hn = x3 * ftanh(cn);
            h_out[(size_t)row * 256 + unit] = f2bf(hn);
            c_out[(size_t)row * 256 + unit] = f2bf(cn);
          }
        }
      }
    }
    return;
  }

#pragma unroll
  for (int tn = 0; tn < 4; ++tn) {
    int col = n0 + wn + tn * 16 + lr;
#pragma unroll
    for (int tm = 0; tm < 4; ++tm) {
#pragma unroll
      for (int r = 0; r < 4; ++r) {
        int row = m0 + wm + tm * 16 + quad * 4 + r;
        if (row >= M) continue;
        float v = acc[tm][tn][r];
        if (isg) {
          gates[(size_t)row * 1024 + (col - 256)] = f2bf(v);
        } else if (mode == MODE_PPA) {
          ppa[(size_t)(ppoff + row) * 256 + col] = f2bf(v);
        } else if (mode == MODE_UPROJ || mode == MODE_FUSE) {
          uproj[(size_t)row * 256 + col] = v;
        } else {  // MODE_ROOT: node index = row * NPER
          hpred[(size_t)row * NPER * 256 + col] = f2bf(ftanh(v));
        }
      }
    }
  }
}

// ---------------- LSTM / assemble elementwise device fns (no LDS) -----------

__device__ __forceinline__ void dev_s0(int r, const u16* __restrict__ wihT,
    const float* __restrict__ bias, const int* __restrict__ feat,
    u16* __restrict__ h, u16* __restrict__ c) {
  int u = threadIdx.x;
  int off, pcs, start; ladder(r, off, pcs, start);
  int lg = r - off;
  int t = lg >> pcs, j = lg & ((1 << pcs) - 1);
  int lab = feat[t * NPER + start + 4 * j];
  const u16* wr = wihT + lab * 1024;
  float gi = b2f(wr[u])       + bias[u];
  float gg = b2f(wr[512 + u]) + bias[512 + u];
  float go = b2f(wr[768 + u]) + bias[768 + u];
  float cn = fsigm(gi) * ftanh(gg);
  float hn = fsigm(go) * ftanh(cn);
  h[(size_t)r * 256 + u] = f2bf(hn);
  c[(size_t)r * 256 + u] = f2bf(cn);
}

__device__ __forceinline__ void dev_lstm_par(int g,
    const u16* __restrict__ gates, const u16* __restrict__ wihT,
    const float* __restrict__ bias, const u16* __restrict__ c_in,
    const int* __restrict__ feat, u16* __restrict__ h, u16* __restrict__ c,
    int lsbits, int start) {
  int u = threadIdx.x;
  int t = g >> lsbits, p = g & ((1 << lsbits) - 1);
  int pr = lsbits ? ((t << (lsbits - 2)) | (p >> 2)) : g;
  int lab = feat[t * NPER + start + p];
  const u16* wr = wihT + lab * 1024;
  const u16* gr = gates + (size_t)pr * 1024;
  float gi = b2f(wr[u])       + bias[u]       + b2f(gr[u]);
  float gf = b2f(wr[256 + u]) + bias[256 + u] + b2f(gr[256 + u]);
  float gg = b2f(wr[512 + u]) + bias[512 + u] + b2f(gr[512 + u]);
  float go = b2f(wr[768 + u]) + bias[768 + u] + b2f(gr[768 + u]);
  float cv = c_in ? b2f(c_in[(size_t)pr * 256 + u]) : 0.f;
  float cn = fsigm(gf) * cv + fsigm(gi) * ftanh(gg);
  float hn = fsigm(go) * ftanh(cn);
  h[(size_t)g * 256 + u] = f2bf(hn);
  c[(size_t)g * 256 + u] = f2bf(cn);
}

// assemble chain row r: hpred rows s=0..3 = tanh(PPA[r] (+ U_s[r]))
__device__ __forceinline__ void dev_assemble(int r,
    const u16* __restrict__ PPA, const float* __restrict__ U1,
    const float* __restrict__ U2, const float* __restrict__ U3,
    u16* __restrict__ HPRED) {
  int u = threadIdx.x;
  int off, pcs, start; ladder(r, off, pcs, start);
  int lg = r - off;
  int t = lg >> pcs, j = lg & ((1 << pcs) - 1);
  size_t base = ((size_t)(t * NPER + start + 4 * j)) * 256 + u;
  size_t ro = (size_t)r * 256 + u;
  float pp = b2f(PPA[ro]);
  HPRED[base]       = f2bf(ftanh(pp));
  HPRED[base + 256] = f2bf(ftanh(pp + U1[ro]));
  HPRED[base + 512] = f2bf(ftanh(pp + U2[ro]));
  HPRED[base + 768] = f2bf(ftanh(pp + U3[ro]));
}

// ---------------- launch kernels --------------------------------------------

__global__ __launch_bounds__(256) void k_s0(
    const u16* WIHST, const float* BS, const int* feat, u16* h, u16* c) {
  dev_s0(blockIdx.x, WIHST, BS, feat, h, c);
}

// GEMM || GEMM (shared 20KB LDS). Side B may be MODE_FUSE.
__global__ __launch_bounds__(256) void k_gg(
    int nA,
    const u16* Aa, const u16* Ba, int Ma, int nxa, int modea,
    u16* ppaa, int ppoffa, float* uproja, u16* gatesa, u16* hpreda,
    const u16* Ab, const u16* Bb, int Mb, int nxb, int modeb,
    u16* ppab, int ppoffb, float* uprojb, u16* gatesb, u16* hpredb,
    int kSib, const int* feat, const u16* wih2, const float* bs2,
    const u16* c_in, u16* h_out, u16* c_out) {
  int b = blockIdx.x;
  if (b < nA)
    dev_dual(b, nxa, Aa, Ba, Ma, modea, ppaa, ppoffa, uproja, gatesa, hpreda,
             0, nullptr, nullptr, nullptr, nullptr, nullptr, nullptr);
  else
    dev_dual(b - nA, nxb, Ab, Bb, Mb, modeb, ppab, ppoffb, uprojb, gatesb,
             hpredb, kSib, feat, wih2, bs2, c_in, h_out, c_out);
}

// GEMM standalone (no fuse)
__global__ __launch_bounds__(256) void k_gemm(
    const u16* A, const u16* B, int M, int nx, int mode,
    u16* ppa, int ppoff, float* uproj, u16* gates, u16* hpred) {
  dev_dual(blockIdx.x, nx, A, B, M, mode, ppa, ppoff, uproj, gates, hpred,
           0, nullptr, nullptr, nullptr, nullptr, nullptr, nullptr);
}

// LSTM standalone
__global__ __launch_bounds__(256) void k_plstm(
    const u16* gatesP, const u16* WIHPT, const float* BP, const u16* cpin,
    const int* feat, u16* hpout, u16* cpout, int lsbits, int start) {
  dev_lstm_par(blockIdx.x, gatesP, WIHPT, BP, cpin, feat, hpout, cpout,
               lsbits, start);
}

// L12: plstm4 (16384) || assembleA (chain rows 0..5440) — both LDS-free
__global__ __launch_bounds__(256) void k_plstm_asm(
    const u16* gatesP, const u16* WIHPT, const float* BP, const u16* cpin,
    const int* feat, u16* hpout, u16* cpout,
    const u16* PPA, const float* U1, const float* U2, const float* U3,
    u16* HPRED) {
  int b = blockIdx.x;
  if (b < 16384)
    dev_lstm_par(b, gatesP, WIHPT, BP, cpin, feat, hpout, cpout, 8, 85);
  else
    dev_assemble(b - 16384, PPA, U1, U2, U3, HPRED);
}

// L14: assembleB (chain rows 5440..21824)
__global__ __launch_bounds__(256) void k_assemble(
    const u16* PPA, const float* U1, const float* U2, const float* U3,
    u16* HPRED) {
  dev_assemble(5440 + blockIdx.x, PPA, U1, U2, U3, HPRED);
}

// ---------------- fused tail: logits GEMM + log-softmax ---------------------
__global__ __launch_bounds__(256, 2) void k_mm_tail(
    const u16* __restrict__ A, const u16* __restrict__ B,
    const float* __restrict__ bias, float* __restrict__ out) {
  __shared__ __align__(16) u16 As[32 * 264];
  __shared__ float smax[32][4], ssum[32][4], slz[32];
  const int m0 = blockIdx.x * 32;
  const int tid = threadIdx.x;
  const int wave = tid >> 6, lane = tid & 63;
  const int quad = lane >> 4, lr = lane & 15;
  const int c0 = wave * 160;

#pragma unroll
  for (int c = 0; c < 4; ++c) {
    int idx = c * 256 + tid;
    int row = idx >> 5, ch = (idx & 31) << 3;
    *(bf16x8*)&As[row * 264 + ch] =
        *(const bf16x8*)(A + (size_t)(m0 + row) * 256 + ch);
  }
  __syncthreads();

  f32x4 acc[2][10] = {};
#pragma unroll
  for (int t = 0; t < 8; ++t) {
    bf16x8 af[2], bfr[10];
#pragma unroll
    for (int tm = 0; tm < 2; ++tm)
      af[tm] = *(const bf16x8*)&As[(tm * 16 + lr) * 264 + t * 32 + quad * 8];
#pragma unroll
    for (int tn = 0; tn < 10; ++tn)
      bfr[tn] = *(const bf16x8*)(B + (size_t)(c0 + tn * 16 + lr) * 256 +
                                 t * 32 + quad * 8);
#pragma unroll
    for (int tm = 0; tm < 2; ++tm)
#pragma unroll
      for (int tn = 0; tn < 10; ++tn)
        acc[tm][tn] = __builtin_amdgcn_mfma_f32_16x16x32_bf16(
            af[tm], bfr[tn], acc[tm][tn], 0, 0, 0);
  }

  float bv[10]; bool val[10];
#pragma unroll
  for (int tn = 0; tn < 10; ++tn) {
    int col = c0 + tn * 16 + lr;
    val[tn] = (col < VDIM);
    bv[tn] = (col < VD2) ? bias[col] : 0.f;
  }

#pragma unroll
  for (int tm = 0; tm < 2; ++tm) {
#pragma unroll
    for (int r = 0; r < 4; ++r) {
      float mx = -1e30f;
#pragma unroll
      for (int tn = 0; tn < 10; ++tn)
        if (val[tn]) mx = fmaxf(mx, acc[tm][tn][r] + bv[tn]);
#pragma unroll
      for (int o = 1; o < 16; o <<= 1) mx = fmaxf(mx, __shfl_xor(mx, o, 64));
      if (lr == 0) smax[tm * 16 + quad * 4 + r][wave] = mx;
    }
  }
  __syncthreads();
#pragma unroll
  for (int tm = 0; tm < 2; ++tm) {
#pragma unroll
    for (int r = 0; r < 4; ++r) {
      int row = tm * 16 + quad * 4 + r;
      float fm = fmaxf(fmaxf(smax[row][0], smax[row][1]),
                       fmaxf(smax[row][2], smax[row][3]));
      float se = 0.f;
#pragma unroll
      for (int tn = 0; tn < 10; ++tn)
        if (val[tn]) se += __expf(acc[tm][tn][r] + bv[tn] - fm);
#pragma unroll
      for (int o = 1; o < 16; o <<= 1) se += __shfl_xor(se, o, 64);
      if (lr == 0) ssum[row][wave] = se;
    }
  }
  __syncthreads();
  if (tid < 32) {
    float fm = fmaxf(fmaxf(smax[tid][0], smax[tid][1]),
                     fmaxf(smax[tid][2], smax[tid][3]));
    slz[tid] = fm + __logf(ssum[tid][0] + ssum[tid][1] +
                           ssum[tid][2] + ssum[tid][3]);
  }
  __syncthreads();

#pragma unroll
  for (int tm = 0; tm < 2; ++tm) {
#pragma unroll
    for (int tn = 0; tn < 10; ++tn) {
      int col = c0 + tn * 16 + lr;
      if (col >= VD2) continue;
#pragma unroll
      for (int r = 0; r < 4; ++r) {
        int row = tm * 16 + quad * 4 + r;
        float v = acc[tm][tn][r] + bv[tn];
        out[(size_t)(m0 + row) * VD2 + col] =
            (col < VDIM) ? (v - slz[row]) : fsigm(v);
      }
    }
  }
}

// ---------------- host ------------------------------------------------------

extern "C" void kernel_launch(void* const* d_in, const int* in_sizes, int n_in,
                              void* d_out, int out_size, void* d_ws, size_t ws_size,
                              hipStream_t stream) {
  const float* z    = (const float*)d_in[0];
  const int*   feat = (const int*)d_in[1];
  const float* Wihp = (const float*)d_in[2];
  const float* Whhp = (const float*)d_in[3];
  const float* bihp = (const float*)d_in[4];
  const float* bhhp = (const float*)d_in[5];
  const float* Wihs = (const float*)d_in[6];
  const float* Whhs = (const float*)d_in[7];
  const float* bihs = (const float*)d_in[8];
  const float* bhhs = (const float*)d_in[9];
  const float* Upar = (const float*)d_in[10];
  const float* Usib = (const float*)d_in[11];
  const float* Wlab = (const float*)d_in[12];
  const float* blab = (const float*)d_in[13];
  const float* Wd   = (const float*)d_in[14];
  const float* bd   = (const float*)d_in[15];
  const float* Ww   = (const float*)d_in[16];
  const float* bw   = (const float*)d_in[17];
  float* out = (float*)d_out;

  char* w = (char*)d_ws;
  auto alloc = [&](size_t bytes) {
    char* p = w; w += (bytes + 255) & ~(size_t)255; return p;
  };
  u16*   UPWHHP = (u16*)alloc((size_t)1280 * 256 * 2);
  u16*   USWHHS = (u16*)alloc((size_t)1280 * 256 * 2);
  u16*   ZBF    = (u16*)alloc((size_t)128 * 256 * 2);   // rows 64..127 pad
  u16*   WIHPT  = (u16*)alloc((size_t)VDIM * 1024 * 2);
  u16*   WIHST  = (u16*)alloc((size_t)VDIM * 1024 * 2);
  u16*   WEXT   = (u16*)alloc((size_t)640 * 256 * 2);   // rows 602..639 pad
  float* BE     = (float*)alloc(VD2 * 4);
  float* BP     = (float*)alloc(1024 * 4);
  float* BS     = (float*)alloc(1024 * 4);
  u16*   WIHST2 = (u16*)alloc((size_t)VDIM * 1024 * 2); // gate-interleaved
  float* BS2    = (float*)alloc(1024 * 4);
  const size_t CR = 21888;                              // 171*128 chain rows
  u16*   HSA[3], *CSA[3];
  for (int k = 0; k < 3; ++k) {
    HSA[k] = (u16*)alloc(CR * 256 * 2);
    CSA[k] = (u16*)alloc(CR * 256 * 2);
  }
  float* UPROJ[3];
  for (int k = 0; k < 3; ++k) UPROJ[k] = (float*)alloc(CR * 256 * 4);
  u16*   PPA   = (u16*)alloc(CR * 256 * 2);             // all chain rows
  const size_t SB = (size_t)16384 * 256 * 2;
  u16* HP[2] = {(u16*)alloc(SB), (u16*)alloc(SB)};
  u16* CP[2] = {(u16*)alloc(SB), (u16*)alloc(SB)};
  u16*   GATESP = (u16*)alloc((size_t)4096 * 1024 * 2);
  u16*   HPRED  = (u16*)alloc((size_t)87424 * 256 * 2); // node-ordered, +pad

  // L1: pack (2672730 elements)
  k_pack<<<10441, 256, 0, stream>>>(Upar, Whhp, Usib, Whhs, z, Wihp, Wihs,
                                    Wlab, Wd, Ww, blab, bd, bw, bihp, bhhp,
                                    bihs, bhhs, UPWHHP, USWHHS, ZBF, WIHPT,
                                    WIHST, WEXT, BE, BP, BS, WIHST2, BS2);
  // L2: s0 (LDS-free, full occupancy)
  k_s0<<<21824, 256, 0, stream>>>(WIHST, BS, feat, HSA[0], CSA[0]);
  // L3: zdual (10, roots->HPRED + gatesP) || sibdual1-FUSE (1710)
  k_gg<<<10 + 1710, 256, 0, stream>>>(
      10,
      ZBF, UPWHHP, 64, 1, MODE_ROOT, nullptr, 0, nullptr, GATESP, HPRED,
      HSA[0], USWHHS, 21824, 171, MODE_FUSE, nullptr, 0, UPROJ[0], nullptr,
      nullptr,
      1, feat, WIHST2, BS2, CSA[0], HSA[1], CSA[1]);
  // L4: plstm0 (64)
  k_plstm<<<64, 256, 0, stream>>>(GATESP, WIHPT, BP, nullptr, feat,
                                  HP[0], CP[0], 0, 0);
  // L5: pdual1 (10) || sibdual2-FUSE (1710)
  k_gg<<<10 + 1710, 256, 0, stream>>>(
      10,
      HP[0], UPWHHP, 64, 1, MODE_PPA, PPA, 0, nullptr, GATESP, nullptr,
      HSA[1], USWHHS, 21824, 171, MODE_FUSE, nullptr, 0, UPROJ[1], nullptr,
      nullptr,
      2, feat, WIHST2, BS2, CSA[1], HSA[2], CSA[2]);
  // L6: plstm1 (256)
  k_plstm<<<256, 256, 0, stream>>>(GATESP, WIHPT, BP, CP[0], feat,
                                   HP[1], CP[1], 2, 1);
  // L7: pdual2 (20) || sibdual3 (342, UPROJ only)
  k_gg<<<20 + 342, 256, 0, stream>>>(
      20,
      HP[1], UPWHHP, 256, 2, MODE_PPA, PPA, 64, nullptr, GATESP, nullptr,
      HSA[2], USWHHS, 21824, 171, MODE_UPROJ, nullptr, 0, UPROJ[2], nullptr,
      nullptr,
      0, nullptr, nullptr, nullptr, nullptr, nullptr, nullptr);
  // L8: plstm2 (1024)
  k_plstm<<<1024, 256, 0, stream>>>(GATESP, WIHPT, BP, CP[1], feat,
                                    HP[0], CP[0], 4, 5);
  // L9: pdual3 (80)
  k_gemm<<<80, 256, 0, stream>>>(HP[0], UPWHHP, 1024, 8, MODE_PPA,
                                 PPA, 320, nullptr, GATESP, nullptr);
  // L10: plstm3 (4096)
  k_plstm<<<4096, 256, 0, stream>>>(GATESP, WIHPT, BP, CP[0], feat,
                                    HP[1], CP[1], 6, 21);
  // L11: pdual4 (320)
  k_gemm<<<320, 256, 0, stream>>>(HP[1], UPWHHP, 4096, 32, MODE_PPA,
                                  PPA, 1344, nullptr, GATESP, nullptr);
  // L12: plstm4 (16384) || assembleA (5440: chain rows 0..5440)
  k_plstm_asm<<<16384 + 5440, 256, 0, stream>>>(
      GATESP, WIHPT, BP, CP[1], feat, HP[0], CP[0],
      PPA, UPROJ[0], UPROJ[1], UPROJ[2], HPRED);
  // L13: pdual5 (256, PPA only, ny=2)
  k_gemm<<<256, 256, 0, stream>>>(HP[0], UPWHHP, 16384, 128, MODE_PPA,
                                  PPA, 5440, nullptr, nullptr, nullptr);
  // L14: assembleB (16384: chain rows 5440..21824)
  k_assemble<<<16384, 256, 0, stream>>>(PPA, UPROJ[0], UPROJ[1], UPROJ[2],
                                        HPRED);
  // L15: fused tail (GEMM + log-softmax, HPRED reader)
  k_mm_tail<<<2730, 256, 0, stream>>>(HPRED, WEXT, BE, out);

  (void)in_sizes; (void)n_in; (void)out_size; (void)ws_size;
}

// Round 12
// 603.321 us; speedup vs baseline: 1.3574x; 1.3574x over previous
//
#include <hip/hip_runtime.h>

// TreeLstmDecoder: B=64 trees, K=4, D=6, V=600, L=256, N_PER=1365, N=87360.
// 15-launch schedule == R10 (measured 620us) with ONE change: the tail is
// 512-thread / 8-wave blocks (32 rows, wave owns 5 col-tiles, acc[2][5] =
// 40 AGPR) for ~2x occupancy on the latency-bound logits GEMM.
//  L1  k_pack
//  L2  k_s0                  (21824 sibling s=0 states, LDS-free)
//  L3  zdual || sibdual1     [GEMM: HPRED roots + gatesP ; UPROJ1+gates]
//  L4  plstm0 || siblstm1    [LSTM, LDS-free]
//  L5  pdual1 || sibdual2    [GEMM: PPA d1+gatesP ; UPROJ2+gates]
//  L6  plstm1 || siblstm2
//  L7  pdual2 || sibdual3    [GEMM: PPA d2+gatesP ; UPROJ3 only]
//  L8  plstm2   L9 pdual3   L10 plstm3   L11 pdual4
//  L12 plstm4 || assembleA (chain rows 0..5440)
//  L13 pdual5 (PPA d5)
//  L14 assembleB (chain rows 5440..21824)
//  L15 k_mm_tail (87360x602x256 GEMM + log-softmax, 512-thread blocks)
// All GEMMs: C = A*B^T, bf16 operands, fp32 MFMA accumulate. Plain stores
// (R6: nontemporal breaks L2 write-combining). Rule from R9/R11: never fuse
// elementwise work into a low-occupancy GEMM epilogue/staging.

typedef unsigned short u16;
typedef short bf16x8 __attribute__((ext_vector_type(8)));
typedef float f32x4 __attribute__((ext_vector_type(4)));

#define NPER 1365
#define VDIM 600
#define VD2  602

#define MODE_PPA   0
#define MODE_UPROJ 1
#define MODE_ROOT  2

__device__ __forceinline__ float b2f(u16 h) {
  union { unsigned u; float f; } v; v.u = ((unsigned)h) << 16; return v.f;
}
__device__ __forceinline__ u16 f2bf(float f) {
  union { float f; unsigned u; } v; v.f = f;
  unsigned r = v.u + 0x7fff + ((v.u >> 16) & 1);
  return (u16)(r >> 16);
}
__device__ __forceinline__ float fsigm(float x) {
  return __fdividef(1.f, 1.f + __expf(-x));
}
__device__ __forceinline__ float ftanh(float x) {
  float e = __expf(-2.f * fabsf(x));
  float r = __fdividef(1.f - e, 1.f + e);
  return x < 0.f ? -r : r;
}

// chain-row ladder: r -> (off, pcs, start) for depths 1..5
__device__ __forceinline__ void ladder(int r, int& off, int& pcs, int& start) {
  if (r < 64)        { off = 0;    pcs = 0; start = 1;   }
  else if (r < 320)  { off = 64;   pcs = 2; start = 5;   }
  else if (r < 1344) { off = 320;  pcs = 4; start = 21;  }
  else if (r < 5440) { off = 1344; pcs = 6; start = 85;  }
  else               { off = 5440; pcs = 8; start = 341; }
}

// ---------------- pack kernel -----------------------------------------------
__global__ void k_pack(
    const float* __restrict__ Upar, const float* __restrict__ Whhp,
    const float* __restrict__ Usib, const float* __restrict__ Whhs,
    const float* __restrict__ z, const float* __restrict__ Wihp,
    const float* __restrict__ Wihs, const float* __restrict__ Wlab,
    const float* __restrict__ Wd, const float* __restrict__ Ww,
    const float* __restrict__ blab, const float* __restrict__ bd,
    const float* __restrict__ bw, const float* __restrict__ bihp,
    const float* __restrict__ bhhp, const float* __restrict__ bihs,
    const float* __restrict__ bhhs,
    u16* __restrict__ UPWHHP, u16* __restrict__ USWHHS, u16* __restrict__ ZBF,
    u16* __restrict__ WIHPT, u16* __restrict__ WIHST, u16* __restrict__ WEXT,
    float* __restrict__ BE, float* __restrict__ BP, float* __restrict__ BS) {
  int i = blockIdx.x * 256 + threadIdx.x;
  if (i < 327680) {
    int r = i >> 8, c = i & 255;
    UPWHHP[i] = f2bf(r < 256 ? Upar[(r << 8) | c] : Whhp[((r - 256) << 8) | c]);
    return;
  }
  i -= 327680;
  if (i < 327680) {
    int r = i >> 8, c = i & 255;
    USWHHS[i] = f2bf(r < 256 ? Usib[(r << 8) | c] : Whhs[((r - 256) << 8) | c]);
    return;
  }
  i -= 327680;
  if (i < 16384) { ZBF[i] = f2bf(z[i]); return; }
  i -= 16384;
  if (i < 614400) {  // W_ih_p [1024,600] -> [600,1024]; coalesced writes
    int r = i >> 10, c = i & 1023;
    WIHPT[i] = f2bf(Wihp[c * VDIM + r]); return;
  }
  i -= 614400;
  if (i < 614400) {
    int r = i >> 10, c = i & 1023;
    WIHST[i] = f2bf(Wihs[c * VDIM + r]); return;
  }
  i -= 614400;
  if (i < VD2 * 256) {
    int r = i >> 8, c = i & 255;
    float v = (r < VDIM) ? Wlab[r * 256 + c] : ((r == VDIM) ? Wd[c] : Ww[c]);
    WEXT[i] = f2bf(v); return;
  }
  i -= VD2 * 256;
  if (i < VD2) { BE[i] = (i < VDIM) ? blab[i] : ((i == VDIM) ? bd[0] : bw[0]); return; }
  i -= VD2;
  if (i < 1024) { BP[i] = bihp[i] + bhhp[i]; return; }
  i -= 1024;
  if (i < 1024) { BS[i] = bihs[i] + bhhs[i]; return; }
}

// ---------------- dual GEMM device fn: C = A*B^T, B=[1280,256] concat -------
// n0>=256 tiles -> gates (bf16 raw). n0<256 tiles by mode:
//  MODE_PPA  : ppa[(ppoff+row)*256+col] = bf16(acc)
//  MODE_UPROJ: uproj[row*256+col] = acc (fp32)
//  MODE_ROOT : hpred[row*NPER*256+col] = bf16(tanh(acc))  (root node rows)
__device__ __forceinline__ void dev_dual(
    int tile, int nx, const u16* __restrict__ A, const u16* __restrict__ B,
    int M, int mode, u16* __restrict__ ppa, int ppoff,
    float* __restrict__ uproj, u16* __restrict__ gates,
    u16* __restrict__ hpred) {
  static __shared__ __align__(16) u16 As[128 * 40];
  static __shared__ __align__(16) u16 Bs[128 * 40];
  const int m0 = (tile % nx) * 128, n0 = (tile / nx) * 128;
  const int tid = threadIdx.x;
  const int wave = tid >> 6, lane = tid & 63;
  const int quad = lane >> 4, lr = lane & 15;
  const int wm = (wave >> 1) * 64, wn = (wave & 1) * 64;
  const int srow = tid >> 2;
  const int sch = (tid & 3) << 3;

  f32x4 acc[4][4] = {};
  for (int t = 0; t < 8; ++t) {
    const int kk = t * 32;
    bf16x8 a0 = *(const bf16x8*)(A + (size_t)(m0 + srow) * 256 + kk + sch);
    bf16x8 a1 = *(const bf16x8*)(A + (size_t)(m0 + srow + 64) * 256 + kk + sch);
    bf16x8 b0 = *(const bf16x8*)(B + (size_t)(n0 + srow) * 256 + kk + sch);
    bf16x8 b1 = *(const bf16x8*)(B + (size_t)(n0 + srow + 64) * 256 + kk + sch);
    __syncthreads();
    *(bf16x8*)&As[srow * 40 + sch] = a0;
    *(bf16x8*)&As[(srow + 64) * 40 + sch] = a1;
    *(bf16x8*)&Bs[srow * 40 + sch] = b0;
    *(bf16x8*)&Bs[(srow + 64) * 40 + sch] = b1;
    __syncthreads();
    bf16x8 af[4], bfr[4];
#pragma unroll
    for (int tm = 0; tm < 4; ++tm)
      af[tm] = *(const bf16x8*)&As[(wm + tm * 16 + lr) * 40 + quad * 8];
#pragma unroll
    for (int tn = 0; tn < 4; ++tn)
      bfr[tn] = *(const bf16x8*)&Bs[(wn + tn * 16 + lr) * 40 + quad * 8];
#pragma unroll
    for (int tm = 0; tm < 4; ++tm)
#pragma unroll
      for (int tn = 0; tn < 4; ++tn)
        acc[tm][tn] = __builtin_amdgcn_mfma_f32_16x16x32_bf16(
            af[tm], bfr[tn], acc[tm][tn], 0, 0, 0);
  }

  const bool isg = (n0 >= 256);
#pragma unroll
  for (int tn = 0; tn < 4; ++tn) {
    int col = n0 + wn + tn * 16 + lr;
#pragma unroll
    for (int tm = 0; tm < 4; ++tm) {
#pragma unroll
      for (int r = 0; r < 4; ++r) {
        int row = m0 + wm + tm * 16 + quad * 4 + r;
        if (row >= M) continue;
        float v = acc[tm][tn][r];
        if (isg) {
          gates[(size_t)row * 1024 + (col - 256)] = f2bf(v);
        } else if (mode == MODE_PPA) {
          ppa[(size_t)(ppoff + row) * 256 + col] = f2bf(v);
        } else if (mode == MODE_UPROJ) {
          uproj[(size_t)row * 256 + col] = v;
        } else {  // MODE_ROOT: node index = row * NPER
          hpred[(size_t)row * NPER * 256 + col] = f2bf(ftanh(v));
        }
      }
    }
  }
}

// ---------------- LSTM / assemble elementwise device fns (no LDS) -----------

__device__ __forceinline__ void dev_s0(int r, const u16* __restrict__ wihT,
    const float* __restrict__ bias, const int* __restrict__ feat,
    u16* __restrict__ h, u16* __restrict__ c) {
  int u = threadIdx.x;
  int off, pcs, start; ladder(r, off, pcs, start);
  int lg = r - off;
  int t = lg >> pcs, j = lg & ((1 << pcs) - 1);
  int lab = feat[t * NPER + start + 4 * j];
  const u16* wr = wihT + lab * 1024;
  float gi = b2f(wr[u])       + bias[u];
  float gg = b2f(wr[512 + u]) + bias[512 + u];
  float go = b2f(wr[768 + u]) + bias[768 + u];
  float cn = fsigm(gi) * ftanh(gg);
  float hn = fsigm(go) * ftanh(cn);
  h[(size_t)r * 256 + u] = f2bf(hn);
  c[(size_t)r * 256 + u] = f2bf(cn);
}

__device__ __forceinline__ void dev_lstm_sib(int r, int k,
    const u16* __restrict__ gates, const u16* __restrict__ wihT,
    const float* __restrict__ bias, const u16* __restrict__ c_in,
    const int* __restrict__ feat, u16* __restrict__ h, u16* __restrict__ c) {
  int u = threadIdx.x;
  int off, pcs, start; ladder(r, off, pcs, start);
  int lg = r - off;
  int t = lg >> pcs, j = lg & ((1 << pcs) - 1);
  int lab = feat[t * NPER + start + 4 * j + k];
  const u16* wr = wihT + lab * 1024;
  const u16* gr = gates + (size_t)r * 1024;
  float gi = b2f(wr[u])       + bias[u]       + b2f(gr[u]);
  float gf = b2f(wr[256 + u]) + bias[256 + u] + b2f(gr[256 + u]);
  float gg = b2f(wr[512 + u]) + bias[512 + u] + b2f(gr[512 + u]);
  float go = b2f(wr[768 + u]) + bias[768 + u] + b2f(gr[768 + u]);
  float cv = b2f(c_in[(size_t)r * 256 + u]);
  float cn = fsigm(gf) * cv + fsigm(gi) * ftanh(gg);
  float hn = fsigm(go) * ftanh(cn);
  h[(size_t)r * 256 + u] = f2bf(hn);
  c[(size_t)r * 256 + u] = f2bf(cn);
}

__device__ __forceinline__ void dev_lstm_par(int g,
    const u16* __restrict__ gates, const u16* __restrict__ wihT,
    const float* __restrict__ bias, const u16* __restrict__ c_in,
    const int* __restrict__ feat, u16* __restrict__ h, u16* __restrict__ c,
    int lsbits, int start) {
  int u = threadIdx.x;
  int t = g >> lsbits, p = g & ((1 << lsbits) - 1);
  int pr = lsbits ? ((t << (lsbits - 2)) | (p >> 2)) : g;
  int lab = feat[t * NPER + start + p];
  const u16* wr = wihT + lab * 1024;
  const u16* gr = gates + (size_t)pr * 1024;
  float gi = b2f(wr[u])       + bias[u]       + b2f(gr[u]);
  float gf = b2f(wr[256 + u]) + bias[256 + u] + b2f(gr[256 + u]);
  float gg = b2f(wr[512 + u]) + bias[512 + u] + b2f(gr[512 + u]);
  float go = b2f(wr[768 + u]) + bias[768 + u] + b2f(gr[768 + u]);
  float cv = c_in ? b2f(c_in[(size_t)pr * 256 + u]) : 0.f;
  float cn = fsigm(gf) * cv + fsigm(gi) * ftanh(gg);
  float hn = fsigm(go) * ftanh(cn);
  h[(size_t)g * 256 + u] = f2bf(hn);
  c[(size_t)g * 256 + u] = f2bf(cn);
}

// assemble chain row r: hpred rows s=0..3 = tanh(PPA[r] (+ U_s[r]))
__device__ __forceinline__ void dev_assemble(int r,
    const u16* __restrict__ PPA, const float* __restrict__ U1,
    const float* __restrict__ U2, const float* __restrict__ U3,
    u16* __restrict__ HPRED) {
  int u = threadIdx.x;
  int off, pcs, start; ladder(r, off, pcs, start);
  int lg = r - off;
  int t = lg >> pcs, j = lg & ((1 << pcs) - 1);
  size_t base = ((size_t)(t * NPER + start + 4 * j)) * 256 + u;
  size_t ro = (size_t)r * 256 + u;
  float pp = b2f(PPA[ro]);
  HPRED[base]       = f2bf(ftanh(pp));
  HPRED[base + 256] = f2bf(ftanh(pp + U1[ro]));
  HPRED[base + 512] = f2bf(ftanh(pp + U2[ro]));
  HPRED[base + 768] = f2bf(ftanh(pp + U3[ro]));
}

// ---------------- launch kernels --------------------------------------------

__global__ __launch_bounds__(256) void k_s0(
    const u16* WIHST, const float* BS, const int* feat, u16* h, u16* c) {
  dev_s0(blockIdx.x, WIHST, BS, feat, h, c);
}

// GEMM || GEMM (shared 20KB LDS via dev_dual's function-local statics)
__global__ __launch_bounds__(256) void k_gg(
    int nA,
    const u16* Aa, const u16* Ba, int Ma, int nxa, int modea,
    u16* ppaa, int ppoffa, float* uproja, u16* gatesa, u16* hpreda,
    const u16* Ab, const u16* Bb, int Mb, int nxb, int modeb,
    u16* ppab, int ppoffb, float* uprojb, u16* gatesb, u16* hpredb) {
  int b = blockIdx.x;
  if (b < nA)
    dev_dual(b, nxa, Aa, Ba, Ma, modea, ppaa, ppoffa, uproja, gatesa, hpreda);
  else
    dev_dual(b - nA, nxb, Ab, Bb, Mb, modeb, ppab, ppoffb, uprojb, gatesb,
             hpredb);
}

// GEMM standalone
__global__ __launch_bounds__(256) void k_gemm(
    const u16* A, const u16* B, int M, int nx, int mode,
    u16* ppa, int ppoff, float* uproj, u16* gates, u16* hpred) {
  dev_dual(blockIdx.x, nx, A, B, M, mode, ppa, ppoff, uproj, gates, hpred);
}

// LSTM || LSTM (no LDS)
__global__ __launch_bounds__(256) void k_ll(
    int nP,
    const u16* gatesP, const u16* WIHPT, const float* BP, const u16* cpin,
    u16* hpout, u16* cpout, int lsbits, int startp,
    int kS, const u16* gatesS, const u16* WIHST, const float* BS,
    const u16* csin, u16* hsout, u16* csout, const int* feat) {
  int b = blockIdx.x;
  if (b < nP)
    dev_lstm_par(b, gatesP, WIHPT, BP, cpin, feat, hpout, cpout, lsbits,
                 startp);
  else
    dev_lstm_sib(b - nP, kS, gatesS, WIHST, BS, csin, feat, hsout, csout);
}

// LSTM standalone
__global__ __launch_bounds__(256) void k_plstm(
    const u16* gatesP, const u16* WIHPT, const float* BP, const u16* cpin,
    const int* feat, u16* hpout, u16* cpout, int lsbits, int start) {
  dev_lstm_par(blockIdx.x, gatesP, WIHPT, BP, cpin, feat, hpout, cpout,
               lsbits, start);
}

// L12: plstm4 (16384) || assembleA (chain rows 0..5440) — both LDS-free
__global__ __launch_bounds__(256) void k_plstm_asm(
    const u16* gatesP, const u16* WIHPT, const float* BP, const u16* cpin,
    const int* feat, u16* hpout, u16* cpout,
    const u16* PPA, const float* U1, const float* U2, const float* U3,
    u16* HPRED) {
  int b = blockIdx.x;
  if (b < 16384)
    dev_lstm_par(b, gatesP, WIHPT, BP, cpin, feat, hpout, cpout, 8, 85);
  else
    dev_assemble(b - 16384, PPA, U1, U2, U3, HPRED);
}

// L14: assembleB (chain rows 5440..21824)
__global__ __launch_bounds__(256) void k_assemble(
    const u16* PPA, const float* U1, const float* U2, const float* U3,
    u16* HPRED) {
  dev_assemble(5440 + blockIdx.x, PPA, U1, U2, U3, HPRED);
}

// ---------------- fused tail: logits GEMM + log-softmax ---------------------
// 512 threads / 8 waves per block, 32 rows. Wave w owns cols [w*80, w*80+80)
// as 5 col-tiles of 16; acc[2][5] f32x4 (40 AGPR) -> ~2x occupancy vs the
// 4-wave version. MFMA:B-load ratio unchanged at 2:1.
__global__ __launch_bounds__(512, 4) void k_mm_tail(
    const u16* __restrict__ A, const u16* __restrict__ B,
    const float* __restrict__ bias, float* __restrict__ out) {
  __shared__ __align__(16) u16 As[32 * 264];
  __shared__ float smax[32][8], ssum[32][8], slz[32];
  const int m0 = blockIdx.x * 32;
  const int tid = threadIdx.x;
  const int wave = tid >> 6, lane = tid & 63;
  const int quad = lane >> 4, lr = lane & 15;
  const int c0 = wave * 80;

#pragma unroll
  for (int c = 0; c < 2; ++c) {
    int idx = c * 512 + tid;
    int row = idx >> 5, ch = (idx & 31) << 3;
    *(bf16x8*)&As[row * 264 + ch] =
        *(const bf16x8*)(A + (size_t)(m0 + row) * 256 + ch);
  }
  __syncthreads();

  f32x4 acc[2][5] = {};
#pragma unroll
  for (int t = 0; t < 8; ++t) {
    bf16x8 af[2], bfr[5];
#pragma unroll
    for (int tm = 0; tm < 2; ++tm)
      af[tm] = *(const bf16x8*)&As[(tm * 16 + lr) * 264 + t * 32 + quad * 8];
#pragma unroll
    for (int tn = 0; tn < 5; ++tn)
      bfr[tn] = *(const bf16x8*)(B + (size_t)(c0 + tn * 16 + lr) * 256 +
                                 t * 32 + quad * 8);
#pragma unroll
    for (int tm = 0; tm < 2; ++tm)
#pragma unroll
      for (int tn = 0; tn < 5; ++tn)
        acc[tm][tn] = __builtin_amdgcn_mfma_f32_16x16x32_bf16(
            af[tm], bfr[tn], acc[tm][tn], 0, 0, 0);
  }

  float bv[5]; bool val[5];
#pragma unroll
  for (int tn = 0; tn < 5; ++tn) {
    int col = c0 + tn * 16 + lr;
    val[tn] = (col < VDIM);
    bv[tn] = (col < VD2) ? bias[col] : 0.f;
  }

#pragma unroll
  for (int tm = 0; tm < 2; ++tm) {
#pragma unroll
    for (int r = 0; r < 4; ++r) {
      float mx = -1e30f;
#pragma unroll
      for (int tn = 0; tn < 5; ++tn)
        if (val[tn]) mx = fmaxf(mx, acc[tm][tn][r] + bv[tn]);
#pragma unroll
      for (int o = 1; o < 16; o <<= 1) mx = fmaxf(mx, __shfl_xor(mx, o, 64));
      if (lr == 0) smax[tm * 16 + quad * 4 + r][wave] = mx;
    }
  }
  __syncthreads();
#pragma unroll
  for (int tm = 0; tm < 2; ++tm) {
#pragma unroll
    for (int r = 0; r < 4; ++r) {
      int row = tm * 16 + quad * 4 + r;
      float fm = smax[row][0];
#pragma unroll
      for (int wv = 1; wv < 8; ++wv) fm = fmaxf(fm, smax[row][wv]);
      float se = 0.f;
#pragma unroll
      for (int tn = 0; tn < 5; ++tn)
        if (val[tn]) se += __expf(acc[tm][tn][r] + bv[tn] - fm);
#pragma unroll
      for (int o = 1; o < 16; o <<= 1) se += __shfl_xor(se, o, 64);
      if (lr == 0) ssum[row][wave] = se;
    }
  }
  __syncthreads();
  if (tid < 32) {
    float fm = smax[tid][0];
#pragma unroll
    for (int wv = 1; wv < 8; ++wv) fm = fmaxf(fm, smax[tid][wv]);
    float ss = 0.f;
#pragma unroll
    for (int wv = 0; wv < 8; ++wv) ss += ssum[tid][wv];
    slz[tid] = fm + __logf(ss);
  }
  __syncthreads();

#pragma unroll
  for (int tm = 0; tm < 2; ++tm) {
#pragma unroll
    for (int tn = 0; tn < 5; ++tn) {
      int col = c0 + tn * 16 + lr;
      if (col >= VD2) continue;
#pragma unroll
      for (int r = 0; r < 4; ++r) {
        int row = tm * 16 + quad * 4 + r;
        float v = acc[tm][tn][r] + bv[tn];
        out[(size_t)(m0 + row) * VD2 + col] =
            (col < VDIM) ? (v - slz[row]) : fsigm(v);
      }
    }
  }
}

// ---------------- host ------------------------------------------------------

extern "C" void kernel_launch(void* const* d_in, const int* in_sizes, int n_in,
                              void* d_out, int out_size, void* d_ws, size_t ws_size,
                              hipStream_t stream) {
  const float* z    = (const float*)d_in[0];
  const int*   feat = (const int*)d_in[1];
  const float* Wihp = (const float*)d_in[2];
  const float* Whhp = (const float*)d_in[3];
  const float* bihp = (const float*)d_in[4];
  const float* bhhp = (const float*)d_in[5];
  const float* Wihs = (const float*)d_in[6];
  const float* Whhs = (const float*)d_in[7];
  const float* bihs = (const float*)d_in[8];
  const float* bhhs = (const float*)d_in[9];
  const float* Upar = (const float*)d_in[10];
  const float* Usib = (const float*)d_in[11];
  const float* Wlab = (const float*)d_in[12];
  const float* blab = (const float*)d_in[13];
  const float* Wd   = (const float*)d_in[14];
  const float* bd   = (const float*)d_in[15];
  const float* Ww   = (const float*)d_in[16];
  const float* bw   = (const float*)d_in[17];
  float* out = (float*)d_out;

  char* w = (char*)d_ws;
  auto alloc = [&](size_t bytes) {
    char* p = w; w += (bytes + 255) & ~(size_t)255; return p;
  };
  u16*   UPWHHP = (u16*)alloc((size_t)1280 * 256 * 2);
  u16*   USWHHS = (u16*)alloc((size_t)1280 * 256 * 2);
  u16*   ZBF    = (u16*)alloc((size_t)128 * 256 * 2);   // rows 64..127 pad
  u16*   WIHPT  = (u16*)alloc((size_t)VDIM * 1024 * 2);
  u16*   WIHST  = (u16*)alloc((size_t)VDIM * 1024 * 2);
  u16*   WEXT   = (u16*)alloc((size_t)640 * 256 * 2);   // rows 602..639 pad
  float* BE     = (float*)alloc(VD2 * 4);
  float* BP     = (float*)alloc(1024 * 4);
  float* BS     = (float*)alloc(1024 * 4);
  const size_t CR = 21888;                              // 171*128 chain rows
  u16*   HSA[3], *CSA[3];
  for (int k = 0; k < 3; ++k) {
    HSA[k] = (u16*)alloc(CR * 256 * 2);
    CSA[k] = (u16*)alloc(CR * 256 * 2);
  }
  float* UPROJ[3];
  for (int k = 0; k < 3; ++k) UPROJ[k] = (float*)alloc(CR * 256 * 4);
  u16*   PPA   = (u16*)alloc(CR * 256 * 2);             // all chain rows
  const size_t SB = (size_t)16384 * 256 * 2;
  u16* HP[2] = {(u16*)alloc(SB), (u16*)alloc(SB)};
  u16* CP[2] = {(u16*)alloc(SB), (u16*)alloc(SB)};
  u16*   GATES  = (u16*)alloc(CR * 1024 * 2);
  u16*   GATESP = (u16*)alloc((size_t)4096 * 1024 * 2);
  u16*   HPRED  = (u16*)alloc((size_t)87424 * 256 * 2); // node-ordered, +pad

  // L1: pack
  k_pack<<<8037, 256, 0, stream>>>(Upar, Whhp, Usib, Whhs, z, Wihp, Wihs,
                                   Wlab, Wd, Ww, blab, bd, bw, bihp, bhhp,
                                   bihs, bhhs, UPWHHP, USWHHS, ZBF, WIHPT,
                                   WIHST, WEXT, BE, BP, BS);
  // L2: s0 (LDS-free, full occupancy)
  k_s0<<<21824, 256, 0, stream>>>(WIHST, BS, feat, HSA[0], CSA[0]);
  // L3: zdual (10, roots -> HPRED) || sibdual1 (1710)
  k_gg<<<10 + 1710, 256, 0, stream>>>(
      10,
      ZBF, UPWHHP, 64, 1, MODE_ROOT, nullptr, 0, nullptr, GATESP, HPRED,
      HSA[0], USWHHS, 21824, 171, MODE_UPROJ, nullptr, 0, UPROJ[0], GATES,
      nullptr);
  // L4: plstm0 (64) || siblstm1 (21824)
  k_ll<<<64 + 21824, 256, 0, stream>>>(
      64, GATESP, WIHPT, BP, nullptr, HP[0], CP[0], 0, 0,
      1, GATES, WIHST, BS, CSA[0], HSA[1], CSA[1], feat);
  // L5: pdual1 (10) || sibdual2 (1710)
  k_gg<<<10 + 1710, 256, 0, stream>>>(
      10,
      HP[0], UPWHHP, 64, 1, MODE_PPA, PPA, 0, nullptr, GATESP, nullptr,
      HSA[1], USWHHS, 21824, 171, MODE_UPROJ, nullptr, 0, UPROJ[1], GATES,
      nullptr);
  // L6: plstm1 (256) || siblstm2 (21824)
  k_ll<<<256 + 21824, 256, 0, stream>>>(
      256, GATESP, WIHPT, BP, CP[0], HP[1], CP[1], 2, 1,
      2, GATES, WIHST, BS, CSA[1], HSA[2], CSA[2], feat);
  // L7: pdual2 (20) || sibdual3 (342, UPROJ only)
  k_gg<<<20 + 342, 256, 0, stream>>>(
      20,
      HP[1], UPWHHP, 256, 2, MODE_PPA, PPA, 64, nullptr, GATESP, nullptr,
      HSA[2], USWHHS, 21824, 171, MODE_UPROJ, nullptr, 0, UPROJ[2], nullptr,
      nullptr);
  // L8: plstm2 (1024)
  k_plstm<<<1024, 256, 0, stream>>>(GATESP, WIHPT, BP, CP[1], feat,
                                    HP[0], CP[0], 4, 5);
  // L9: pdual3 (80)
  k_gemm<<<80, 256, 0, stream>>>(HP[0], UPWHHP, 1024, 8, MODE_PPA,
                                 PPA, 320, nullptr, GATESP, nullptr);
  // L10: plstm3 (4096)
  k_plstm<<<4096, 256, 0, stream>>>(GATESP, WIHPT, BP, CP[0], feat,
                                    HP[1], CP[1], 6, 21);
  // L11: pdual4 (320)
  k_gemm<<<320, 256, 0, stream>>>(HP[1], UPWHHP, 4096, 32, MODE_PPA,
                                  PPA, 1344, nullptr, GATESP, nullptr);
  // L12: plstm4 (16384) || assembleA (5440: chain rows 0..5440)
  k_plstm_asm<<<16384 + 5440, 256, 0, stream>>>(
      GATESP, WIHPT, BP, CP[1], feat, HP[0], CP[0],
      PPA, UPROJ[0], UPROJ[1], UPROJ[2], HPRED);
  // L13: pdual5 (256, PPA only, ny=2)
  k_gemm<<<256, 256, 0, stream>>>(HP[0], UPWHHP, 16384, 128, MODE_PPA,
                                  PPA, 5440, nullptr, nullptr, nullptr);
  // L14: assembleB (16384: chain rows 5440..21824)
  k_assemble<<<16384, 256, 0, stream>>>(PPA, UPROJ[0], UPROJ[1], UPROJ[2],
                                        HPRED);
  // L15: fused tail (GEMM + log-softmax, HPRED reader, 512-thread blocks)
  k_mm_tail<<<2730, 512, 0, stream>>>(HPRED, WEXT, BE, out);

  (void)in_sizes; (void)n_in; (void)out_size; (void)ws_size;
}

// Round 13
// 602.831 us; speedup vs baseline: 1.3585x; 1.0008x over previous
//
#include <hip/hip_runtime.h>

// TreeLstmDecoder: B=64 trees, K=4, D=6, V=600, L=256, N_PER=1365, N=87360.
// 15-launch schedule (R12 = 603us) with three mid-section changes:
//  - pack split: L1 packA = LDS-tile transposes (WIHPT/WIHST, coalesced both
//    sides) + BP/BS; L2 = packB (rest of weight pack) || s0 (both LDS-free).
//  - assembleA redistributed by depth readiness: rows 0..320 with plstm2,
//    320..1344 with plstm3, 1344..5440 with plstm4, 5440..21824 after pdual5.
//  - tail unchanged from R12 (512-thread, 32-row, acc[2][5], 41% occ, 144us).
//  L1  k_packA                 (transposes + biases)
//  L2  packB || s0
//  L3  zdual || sibdual1       [GEMM: HPRED roots + gatesP ; UPROJ1+gates]
//  L4  plstm0 || siblstm1      [LSTM, LDS-free]
//  L5  pdual1 || sibdual2
//  L6  plstm1 || siblstm2
//  L7  pdual2 || sibdual3      [PPA d2+gatesP ; UPROJ3 only]
//  L8  plstm2 || asm[0,320)    L9  pdual3
//  L10 plstm3 || asm[320,1344) L11 pdual4
//  L12 plstm4 || asm[1344,5440)
//  L13 pdual5  L14 asm[5440,21824)  L15 k_mm_tail
// Rules learned: plain stores only (R6); never fuse elementwise into a
// low-occupancy GEMM epilogue/staging (R9/R11); merge like-with-like only
// (R7: GEMM LDS poisons elementwise occupancy).

typedef unsigned short u16;
typedef short bf16x8 __attribute__((ext_vector_type(8)));
typedef float f32x4 __attribute__((ext_vector_type(4)));

#define NPER 1365
#define VDIM 600
#define VD2  602

#define MODE_PPA   0
#define MODE_UPROJ 1
#define MODE_ROOT  2

__device__ __forceinline__ float b2f(u16 h) {
  union { unsigned u; float f; } v; v.u = ((unsigned)h) << 16; return v.f;
}
__device__ __forceinline__ u16 f2bf(float f) {
  union { float f; unsigned u; } v; v.f = f;
  unsigned r = v.u + 0x7fff + ((v.u >> 16) & 1);
  return (u16)(r >> 16);
}
__device__ __forceinline__ float fsigm(float x) {
  return __fdividef(1.f, 1.f + __expf(-x));
}
__device__ __forceinline__ float ftanh(float x) {
  float e = __expf(-2.f * fabsf(x));
  float r = __fdividef(1.f - e, 1.f + e);
  return x < 0.f ? -r : r;
}

// chain-row ladder: r -> (off, pcs, start) for depths 1..5
__device__ __forceinline__ void ladder(int r, int& off, int& pcs, int& start) {
  if (r < 64)        { off = 0;    pcs = 0; start = 1;   }
  else if (r < 320)  { off = 64;   pcs = 2; start = 5;   }
  else if (r < 1344) { off = 320;  pcs = 4; start = 21;  }
  else if (r < 5440) { off = 1344; pcs = 6; start = 85;  }
  else               { off = 5440; pcs = 8; start = 341; }
}

// ---------------- L1: packA — LDS-tile transposes + biases ------------------
// Wih [1024,600] fp32 -> WihT [600,1024] bf16, 32x32 tiles, coalesced
// reads AND writes. 608 tiles/matrix (19 r-tiles x 32 c-tiles) x 2 matrices.
__global__ __launch_bounds__(256) void k_packA(
    const float* __restrict__ Wihp, const float* __restrict__ Wihs,
    const float* __restrict__ bihp, const float* __restrict__ bhhp,
    const float* __restrict__ bihs, const float* __restrict__ bhhs,
    u16* __restrict__ WIHPT, u16* __restrict__ WIHST,
    float* __restrict__ BP, float* __restrict__ BS) {
  int b = blockIdx.x;
  if (b < 1216) {
    __shared__ u16 tile[32][34];
    int m = (b >= 608);
    const float* src = m ? Wihs : Wihp;
    u16* dst = m ? WIHST : WIHPT;
    int tb = m ? b - 608 : b;
    int rt = tb >> 5, ct = tb & 31;      // rt over 600-dim (19), ct over 1024
    int r0 = rt * 32, c0 = ct * 32;
    int tx = threadIdx.x & 31, ty = threadIdx.x >> 5;
#pragma unroll
    for (int yy = 0; yy < 32; yy += 8) {
      int c = c0 + ty + yy;              // src row (0..1023)
      int r = r0 + tx;                   // src col (0..599)
      if (r < VDIM) tile[ty + yy][tx] = f2bf(src[(size_t)c * VDIM + r]);
    }
    __syncthreads();
#pragma unroll
    for (int yy = 0; yy < 32; yy += 8) {
      int r = r0 + ty + yy;              // dst row (0..599)
      int c = c0 + tx;
      if (r < VDIM) dst[(size_t)r * 1024 + c] = tile[tx][ty + yy];
    }
    return;
  }
  int i = (b - 1216) * 256 + threadIdx.x;
  if (i < 1024) { BP[i] = bihp[i] + bhhp[i]; return; }
  i -= 1024;
  if (i < 1024) BS[i] = bihs[i] + bhhs[i];
}

// ---------------- LSTM / assemble elementwise device fns (no LDS) -----------

__device__ __forceinline__ void dev_s0(int r, const u16* __restrict__ wihT,
    const float* __restrict__ bias, const int* __restrict__ feat,
    u16* __restrict__ h, u16* __restrict__ c) {
  int u = threadIdx.x;
  int off, pcs, start; ladder(r, off, pcs, start);
  int lg = r - off;
  int t = lg >> pcs, j = lg & ((1 << pcs) - 1);
  int lab = feat[t * NPER + start + 4 * j];
  const u16* wr = wihT + lab * 1024;
  float gi = b2f(wr[u])       + bias[u];
  float gg = b2f(wr[512 + u]) + bias[512 + u];
  float go = b2f(wr[768 + u]) + bias[768 + u];
  float cn = fsigm(gi) * ftanh(gg);
  float hn = fsigm(go) * ftanh(cn);
  h[(size_t)r * 256 + u] = f2bf(hn);
  c[(size_t)r * 256 + u] = f2bf(cn);
}

// ---------------- L2: packB (rest of pack) || s0 ----------------------------
__global__ __launch_bounds__(256) void k_packB_s0(
    const float* __restrict__ Upar, const float* __restrict__ Whhp,
    const float* __restrict__ Usib, const float* __restrict__ Whhs,
    const float* __restrict__ z, const float* __restrict__ Wlab,
    const float* __restrict__ Wd, const float* __restrict__ Ww,
    const float* __restrict__ blab, const float* __restrict__ bd,
    const float* __restrict__ bw,
    u16* __restrict__ UPWHHP, u16* __restrict__ USWHHS, u16* __restrict__ ZBF,
    u16* __restrict__ WEXT, float* __restrict__ BE,
    const u16* __restrict__ WIHST, const float* __restrict__ BS,
    const int* __restrict__ feat, u16* __restrict__ h0, u16* __restrict__ c0) {
  int b = blockIdx.x;
  if (b < 21824) { dev_s0(b, WIHST, BS, feat, h0, c0); return; }
  int i = (b - 21824) * 256 + threadIdx.x;
  if (i < 327680) {
    int r = i >> 8, c = i & 255;
    UPWHHP[i] = f2bf(r < 256 ? Upar[(r << 8) | c] : Whhp[((r - 256) << 8) | c]);
    return;
  }
  i -= 327680;
  if (i < 327680) {
    int r = i >> 8, c = i & 255;
    USWHHS[i] = f2bf(r < 256 ? Usib[(r << 8) | c] : Whhs[((r - 256) << 8) | c]);
    return;
  }
  i -= 327680;
  if (i < 16384) { ZBF[i] = f2bf(z[i]); return; }
  i -= 16384;
  if (i < VD2 * 256) {
    int r = i >> 8, c = i & 255;
    float v = (r < VDIM) ? Wlab[r * 256 + c] : ((r == VDIM) ? Wd[c] : Ww[c]);
    WEXT[i] = f2bf(v); return;
  }
  i -= VD2 * 256;
  if (i < VD2) BE[i] = (i < VDIM) ? blab[i] : ((i == VDIM) ? bd[0] : bw[0]);
}

// ---------------- dual GEMM device fn: C = A*B^T, B=[1280,256] concat -------
__device__ __forceinline__ void dev_dual(
    int tile, int nx, const u16* __restrict__ A, const u16* __restrict__ B,
    int M, int mode, u16* __restrict__ ppa, int ppoff,
    float* __restrict__ uproj, u16* __restrict__ gates,
    u16* __restrict__ hpred) {
  static __shared__ __align__(16) u16 As[128 * 40];
  static __shared__ __align__(16) u16 Bs[128 * 40];
  const int m0 = (tile % nx) * 128, n0 = (tile / nx) * 128;
  const int tid = threadIdx.x;
  const int wave = tid >> 6, lane = tid & 63;
  const int quad = lane >> 4, lr = lane & 15;
  const int wm = (wave >> 1) * 64, wn = (wave & 1) * 64;
  const int srow = tid >> 2;
  const int sch = (tid & 3) << 3;

  f32x4 acc[4][4] = {};
  for (int t = 0; t < 8; ++t) {
    const int kk = t * 32;
    bf16x8 a0 = *(const bf16x8*)(A + (size_t)(m0 + srow) * 256 + kk + sch);
    bf16x8 a1 = *(const bf16x8*)(A + (size_t)(m0 + srow + 64) * 256 + kk + sch);
    bf16x8 b0 = *(const bf16x8*)(B + (size_t)(n0 + srow) * 256 + kk + sch);
    bf16x8 b1 = *(const bf16x8*)(B + (size_t)(n0 + srow + 64) * 256 + kk + sch);
    __syncthreads();
    *(bf16x8*)&As[srow * 40 + sch] = a0;
    *(bf16x8*)&As[(srow + 64) * 40 + sch] = a1;
    *(bf16x8*)&Bs[srow * 40 + sch] = b0;
    *(bf16x8*)&Bs[(srow + 64) * 40 + sch] = b1;
    __syncthreads();
    bf16x8 af[4], bfr[4];
#pragma unroll
    for (int tm = 0; tm < 4; ++tm)
      af[tm] = *(const bf16x8*)&As[(wm + tm * 16 + lr) * 40 + quad * 8];
#pragma unroll
    for (int tn = 0; tn < 4; ++tn)
      bfr[tn] = *(const bf16x8*)&Bs[(wn + tn * 16 + lr) * 40 + quad * 8];
#pragma unroll
    for (int tm = 0; tm < 4; ++tm)
#pragma unroll
      for (int tn = 0; tn < 4; ++tn)
        acc[tm][tn] = __builtin_amdgcn_mfma_f32_16x16x32_bf16(
            af[tm], bfr[tn], acc[tm][tn], 0, 0, 0);
  }

  const bool isg = (n0 >= 256);
#pragma unroll
  for (int tn = 0; tn < 4; ++tn) {
    int col = n0 + wn + tn * 16 + lr;
#pragma unroll
    for (int tm = 0; tm < 4; ++tm) {
#pragma unroll
      for (int r = 0; r < 4; ++r) {
        int row = m0 + wm + tm * 16 + quad * 4 + r;
        if (row >= M) continue;
        float v = acc[tm][tn][r];
        if (isg) {
          gates[(size_t)row * 1024 + (col - 256)] = f2bf(v);
        } else if (mode == MODE_PPA) {
          ppa[(size_t)(ppoff + row) * 256 + col] = f2bf(v);
        } else if (mode == MODE_UPROJ) {
          uproj[(size_t)row * 256 + col] = v;
        } else {  // MODE_ROOT: node index = row * NPER
          hpred[(size_t)row * NPER * 256 + col] = f2bf(ftanh(v));
        }
      }
    }
  }
}

__device__ __forceinline__ void dev_lstm_sib(int r, int k,
    const u16* __restrict__ gates, const u16* __restrict__ wihT,
    const float* __restrict__ bias, const u16* __restrict__ c_in,
    const int* __restrict__ feat, u16* __restrict__ h, u16* __restrict__ c) {
  int u = threadIdx.x;
  int off, pcs, start; ladder(r, off, pcs, start);
  int lg = r - off;
  int t = lg >> pcs, j = lg & ((1 << pcs) - 1);
  int lab = feat[t * NPER + start + 4 * j + k];
  const u16* wr = wihT + lab * 1024;
  const u16* gr = gates + (size_t)r * 1024;
  float gi = b2f(wr[u])       + bias[u]       + b2f(gr[u]);
  float gf = b2f(wr[256 + u]) + bias[256 + u] + b2f(gr[256 + u]);
  float gg = b2f(wr[512 + u]) + bias[512 + u] + b2f(gr[512 + u]);
  float go = b2f(wr[768 + u]) + bias[768 + u] + b2f(gr[768 + u]);
  float cv = b2f(c_in[(size_t)r * 256 + u]);
  float cn = fsigm(gf) * cv + fsigm(gi) * ftanh(gg);
  float hn = fsigm(go) * ftanh(cn);
  h[(size_t)r * 256 + u] = f2bf(hn);
  c[(size_t)r * 256 + u] = f2bf(cn);
}

__device__ __forceinline__ void dev_lstm_par(int g,
    const u16* __restrict__ gates, const u16* __restrict__ wihT,
    const float* __restrict__ bias, const u16* __restrict__ c_in,
    const int* __restrict__ feat, u16* __restrict__ h, u16* __restrict__ c,
    int lsbits, int start) {
  int u = threadIdx.x;
  int t = g >> lsbits, p = g & ((1 << lsbits) - 1);
  int pr = lsbits ? ((t << (lsbits - 2)) | (p >> 2)) : g;
  int lab = feat[t * NPER + start + p];
  const u16* wr = wihT + lab * 1024;
  const u16* gr = gates + (size_t)pr * 1024;
  float gi = b2f(wr[u])       + bias[u]       + b2f(gr[u]);
  float gf = b2f(wr[256 + u]) + bias[256 + u] + b2f(gr[256 + u]);
  float gg = b2f(wr[512 + u]) + bias[512 + u] + b2f(gr[512 + u]);
  float go = b2f(wr[768 + u]) + bias[768 + u] + b2f(gr[768 + u]);
  float cv = c_in ? b2f(c_in[(size_t)pr * 256 + u]) : 0.f;
  float cn = fsigm(gf) * cv + fsigm(gi) * ftanh(gg);
  float hn = fsigm(go) * ftanh(cn);
  h[(size_t)g * 256 + u] = f2bf(hn);
  c[(size_t)g * 256 + u] = f2bf(cn);
}

// assemble chain row r: hpred rows s=0..3 = tanh(PPA[r] (+ U_s[r]))
__device__ __forceinline__ void dev_assemble(int r,
    const u16* __restrict__ PPA, const float* __restrict__ U1,
    const float* __restrict__ U2, const float* __restrict__ U3,
    u16* __restrict__ HPRED) {
  int u = threadIdx.x;
  int off, pcs, start; ladder(r, off, pcs, start);
  int lg = r - off;
  int t = lg >> pcs, j = lg & ((1 << pcs) - 1);
  size_t base = ((size_t)(t * NPER + start + 4 * j)) * 256 + u;
  size_t ro = (size_t)r * 256 + u;
  float pp = b2f(PPA[ro]);
  HPRED[base]       = f2bf(ftanh(pp));
  HPRED[base + 256] = f2bf(ftanh(pp + U1[ro]));
  HPRED[base + 512] = f2bf(ftanh(pp + U2[ro]));
  HPRED[base + 768] = f2bf(ftanh(pp + U3[ro]));
}

// ---------------- launch kernels --------------------------------------------

// GEMM || GEMM (shared 20KB LDS via dev_dual's function-local statics)
__global__ __launch_bounds__(256) void k_gg(
    int nA,
    const u16* Aa, const u16* Ba, int Ma, int nxa, int modea,
    u16* ppaa, int ppoffa, float* uproja, u16* gatesa, u16* hpreda,
    const u16* Ab, const u16* Bb, int Mb, int nxb, int modeb,
    u16* ppab, int ppoffb, float* uprojb, u16* gatesb, u16* hpredb) {
  int b = blockIdx.x;
  if (b < nA)
    dev_dual(b, nxa, Aa, Ba, Ma, modea, ppaa, ppoffa, uproja, gatesa, hpreda);
  else
    dev_dual(b - nA, nxb, Ab, Bb, Mb, modeb, ppab, ppoffb, uprojb, gatesb,
             hpredb);
}

// GEMM standalone
__global__ __launch_bounds__(256) void k_gemm(
    const u16* A, const u16* B, int M, int nx, int mode,
    u16* ppa, int ppoff, float* uproj, u16* gates, u16* hpred) {
  dev_dual(blockIdx.x, nx, A, B, M, mode, ppa, ppoff, uproj, gates, hpred);
}

// LSTM || LSTM (no LDS)
__global__ __launch_bounds__(256) void k_ll(
    int nP,
    const u16* gatesP, const u16* WIHPT, const float* BP, const u16* cpin,
    u16* hpout, u16* cpout, int lsbits, int startp,
    int kS, const u16* gatesS, const u16* WIHST, const float* BS,
    const u16* csin, u16* hsout, u16* csout, const int* feat) {
  int b = blockIdx.x;
  if (b < nP)
    dev_lstm_par(b, gatesP, WIHPT, BP, cpin, feat, hpout, cpout, lsbits,
                 startp);
  else
    dev_lstm_sib(b - nP, kS, gatesS, WIHST, BS, csin, feat, hsout, csout);
}

// plstm (nP blocks) || assemble rows [asmBase, asmBase + gridDim.x - nP)
__global__ __launch_bounds__(256) void k_plstm_asm(
    int nP,
    const u16* gatesP, const u16* WIHPT, const float* BP, const u16* cpin,
    const int* feat, u16* hpout, u16* cpout, int lsbits, int start,
    int asmBase, const u16* PPA, const float* U1, const float* U2,
    const float* U3, u16* HPRED) {
  int b = blockIdx.x;
  if (b < nP)
    dev_lstm_par(b, gatesP, WIHPT, BP, cpin, feat, hpout, cpout, lsbits,
                 start);
  else
    dev_assemble(asmBase + b - nP, PPA, U1, U2, U3, HPRED);
}

// assembleB (chain rows asmBase..)
__global__ __launch_bounds__(256) void k_assemble(
    int asmBase, const u16* PPA, const float* U1, const float* U2,
    const float* U3, u16* HPRED) {
  dev_assemble(asmBase + blockIdx.x, PPA, U1, U2, U3, HPRED);
}

// ---------------- fused tail: logits GEMM + log-softmax (R12, 144us) --------
__global__ __launch_bounds__(512, 4) void k_mm_tail(
    const u16* __restrict__ A, const u16* __restrict__ B,
    const float* __restrict__ bias, float* __restrict__ out) {
  __shared__ __align__(16) u16 As[32 * 264];
  __shared__ float smax[32][8], ssum[32][8], slz[32];
  const int m0 = blockIdx.x * 32;
  const int tid = threadIdx.x;
  const int wave = tid >> 6, lane = tid & 63;
  const int quad = lane >> 4, lr = lane & 15;
  const int c0 = wave * 80;

#pragma unroll
  for (int c = 0; c < 2; ++c) {
    int idx = c * 512 + tid;
    int row = idx >> 5, ch = (idx & 31) << 3;
    *(bf16x8*)&As[row * 264 + ch] =
        *(const bf16x8*)(A + (size_t)(m0 + row) * 256 + ch);
  }
  __syncthreads();

  f32x4 acc[2][5] = {};
#pragma unroll
  for (int t = 0; t < 8; ++t) {
    bf16x8 af[2], bfr[5];
#pragma unroll
    for (int tm = 0; tm < 2; ++tm)
      af[tm] = *(const bf16x8*)&As[(tm * 16 + lr) * 264 + t * 32 + quad * 8];
#pragma unroll
    for (int tn = 0; tn < 5; ++tn)
      bfr[tn] = *(const bf16x8*)(B + (size_t)(c0 + tn * 16 + lr) * 256 +
                                 t * 32 + quad * 8);
#pragma unroll
    for (int tm = 0; tm < 2; ++tm)
#pragma unroll
      for (int tn = 0; tn < 5; ++tn)
        acc[tm][tn] = __builtin_amdgcn_mfma_f32_16x16x32_bf16(
            af[tm], bfr[tn], acc[tm][tn], 0, 0, 0);
  }

  float bv[5]; bool val[5];
#pragma unroll
  for (int tn = 0; tn < 5; ++tn) {
    int col = c0 + tn * 16 + lr;
    val[tn] = (col < VDIM);
    bv[tn] = (col < VD2) ? bias[col] : 0.f;
  }

#pragma unroll
  for (int tm = 0; tm < 2; ++tm) {
#pragma unroll
    for (int r = 0; r < 4; ++r) {
      float mx = -1e30f;
#pragma unroll
      for (int tn = 0; tn < 5; ++tn)
        if (val[tn]) mx = fmaxf(mx, acc[tm][tn][r] + bv[tn]);
#pragma unroll
      for (int o = 1; o < 16; o <<= 1) mx = fmaxf(mx, __shfl_xor(mx, o, 64));
      if (lr == 0) smax[tm * 16 + quad * 4 + r][wave] = mx;
    }
  }
  __syncthreads();
#pragma unroll
  for (int tm = 0; tm < 2; ++tm) {
#pragma unroll
    for (int r = 0; r < 4; ++r) {
      int row = tm * 16 + quad * 4 + r;
      float fm = smax[row][0];
#pragma unroll
      for (int wv = 1; wv < 8; ++wv) fm = fmaxf(fm, smax[row][wv]);
      float se = 0.f;
#pragma unroll
      for (int tn = 0; tn < 5; ++tn)
        if (val[tn]) se += __expf(acc[tm][tn][r] + bv[tn] - fm);
#pragma unroll
      for (int o = 1; o < 16; o <<= 1) se += __shfl_xor(se, o, 64);
      if (lr == 0) ssum[row][wave] = se;
    }
  }
  __syncthreads();
  if (tid < 32) {
    float fm = smax[tid][0];
#pragma unroll
    for (int wv = 1; wv < 8; ++wv) fm = fmaxf(fm, smax[tid][wv]);
    float ss = 0.f;
#pragma unroll
    for (int wv = 0; wv < 8; ++wv) ss += ssum[tid][wv];
    slz[tid] = fm + __logf(ss);
  }
  __syncthreads();

#pragma unroll
  for (int tm = 0; tm < 2; ++tm) {
#pragma unroll
    for (int tn = 0; tn < 5; ++tn) {
      int col = c0 + tn * 16 + lr;
      if (col >= VD2) continue;
#pragma unroll
      for (int r = 0; r < 4; ++r) {
        int row = tm * 16 + quad * 4 + r;
        float v = acc[tm][tn][r] + bv[tn];
        out[(size_t)(m0 + row) * VD2 + col] =
            (col < VDIM) ? (v - slz[row]) : fsigm(v);
      }
    }
  }
}

// ---------------- host ------------------------------------------------------

extern "C" void kernel_launch(void* const* d_in, const int* in_sizes, int n_in,
                              void* d_out, int out_size, void* d_ws, size_t ws_size,
                              hipStream_t stream) {
  const float* z    = (const float*)d_in[0];
  const int*   feat = (const int*)d_in[1];
  const float* Wihp = (const float*)d_in[2];
  const float* Whhp = (const float*)d_in[3];
  const float* bihp = (const float*)d_in[4];
  const float* bhhp = (const float*)d_in[5];
  const float* Wihs = (const float*)d_in[6];
  const float* Whhs = (const float*)d_in[7];
  const float* bihs = (const float*)d_in[8];
  const float* bhhs = (const float*)d_in[9];
  const float* Upar = (const float*)d_in[10];
  const float* Usib = (const float*)d_in[11];
  const float* Wlab = (const float*)d_in[12];
  const float* blab = (const float*)d_in[13];
  const float* Wd   = (const float*)d_in[14];
  const float* bd   = (const float*)d_in[15];
  const float* Ww   = (const float*)d_in[16];
  const float* bw   = (const float*)d_in[17];
  float* out = (float*)d_out;

  char* w = (char*)d_ws;
  auto alloc = [&](size_t bytes) {
    char* p = w; w += (bytes + 255) & ~(size_t)255; return p;
  };
  u16*   UPWHHP = (u16*)alloc((size_t)1280 * 256 * 2);
  u16*   USWHHS = (u16*)alloc((size_t)1280 * 256 * 2);
  u16*   ZBF    = (u16*)alloc((size_t)128 * 256 * 2);   // rows 64..127 pad
  u16*   WIHPT  = (u16*)alloc((size_t)VDIM * 1024 * 2);
  u16*   WIHST  = (u16*)alloc((size_t)VDIM * 1024 * 2);
  u16*   WEXT   = (u16*)alloc((size_t)640 * 256 * 2);   // rows 602..639 pad
  float* BE     = (float*)alloc(VD2 * 4);
  float* BP     = (float*)alloc(1024 * 4);
  float* BS     = (float*)alloc(1024 * 4);
  const size_t CR = 21888;                              // 171*128 chain rows
  u16*   HSA[3], *CSA[3];
  for (int k = 0; k < 3; ++k) {
    HSA[k] = (u16*)alloc(CR * 256 * 2);
    CSA[k] = (u16*)alloc(CR * 256 * 2);
  }
  float* UPROJ[3];
  for (int k = 0; k < 3; ++k) UPROJ[k] = (float*)alloc(CR * 256 * 4);
  u16*   PPA   = (u16*)alloc(CR * 256 * 2);             // all chain rows
  const size_t SB = (size_t)16384 * 256 * 2;
  u16* HP[2] = {(u16*)alloc(SB), (u16*)alloc(SB)};
  u16* CP[2] = {(u16*)alloc(SB), (u16*)alloc(SB)};
  u16*   GATES  = (u16*)alloc(CR * 1024 * 2);
  u16*   GATESP = (u16*)alloc((size_t)4096 * 1024 * 2);
  u16*   HPRED  = (u16*)alloc((size_t)87424 * 256 * 2); // node-ordered, +pad

  // L1: packA — transposes (1216 tile-blocks) + biases (8 blocks)
  k_packA<<<1224, 256, 0, stream>>>(Wihp, Wihs, bihp, bhhp, bihs, bhhs,
                                    WIHPT, WIHST, BP, BS);
  // L2: s0 (21824) || packB (3229 blocks: 826458 elements)
  k_packB_s0<<<21824 + 3229, 256, 0, stream>>>(
      Upar, Whhp, Usib, Whhs, z, Wlab, Wd, Ww, blab, bd, bw,
      UPWHHP, USWHHS, ZBF, WEXT, BE, WIHST, BS, feat, HSA[0], CSA[0]);
  // L3: zdual (10, roots -> HPRED) || sibdual1 (1710)
  k_gg<<<10 + 1710, 256, 0, stream>>>(
      10,
      ZBF, UPWHHP, 64, 1, MODE_ROOT, nullptr, 0, nullptr, GATESP, HPRED,
      HSA[0], USWHHS, 21824, 171, MODE_UPROJ, nullptr, 0, UPROJ[0], GATES,
      nullptr);
  // L4: plstm0 (64) || siblstm1 (21824)
  k_ll<<<64 + 21824, 256, 0, stream>>>(
      64, GATESP, WIHPT, BP, nullptr, HP[0], CP[0], 0, 0,
      1, GATES, WIHST, BS, CSA[0], HSA[1], CSA[1], feat);
  // L5: pdual1 (10) || sibdual2 (1710)
  k_gg<<<10 + 1710, 256, 0, stream>>>(
      10,
      HP[0], UPWHHP, 64, 1, MODE_PPA, PPA, 0, nullptr, GATESP, nullptr,
      HSA[1], USWHHS, 21824, 171, MODE_UPROJ, nullptr, 0, UPROJ[1], GATES,
      nullptr);
  // L6: plstm1 (256) || siblstm2 (21824)
  k_ll<<<256 + 21824, 256, 0, stream>>>(
      256, GATESP, WIHPT, BP, CP[0], HP[1], CP[1], 2, 1,
      2, GATES, WIHST, BS, CSA[1], HSA[2], CSA[2], feat);
  // L7: pdual2 (20) || sibdual3 (342, UPROJ only)
  k_gg<<<20 + 342, 256, 0, stream>>>(
      20,
      HP[1], UPWHHP, 256, 2, MODE_PPA, PPA, 64, nullptr, GATESP, nullptr,
      HSA[2], USWHHS, 21824, 171, MODE_UPROJ, nullptr, 0, UPROJ[2], nullptr,
      nullptr);
  // L8: plstm2 (1024) || assemble rows [0, 320)
  k_plstm_asm<<<1024 + 320, 256, 0, stream>>>(
      1024, GATESP, WIHPT, BP, CP[1], feat, HP[0], CP[0], 4, 5,
      0, PPA, UPROJ[0], UPROJ[1], UPROJ[2], HPRED);
  // L9: pdual3 (80)
  k_gemm<<<80, 256, 0, stream>>>(HP[0], UPWHHP, 1024, 8, MODE_PPA,
                                 PPA, 320, nullptr, GATESP, nullptr);
  // L10: plstm3 (4096) || assemble rows [320, 1344)
  k_plstm_asm<<<4096 + 1024, 256, 0, stream>>>(
      4096, GATESP, WIHPT, BP, CP[0], feat, HP[1], CP[1], 6, 21,
      320, PPA, UPROJ[0], UPROJ[1], UPROJ[2], HPRED);
  // L11: pdual4 (320)
  k_gemm<<<320, 256, 0, stream>>>(HP[1], UPWHHP, 4096, 32, MODE_PPA,
                                  PPA, 1344, nullptr, GATESP, nullptr);
  // L12: plstm4 (16384) || assemble rows [1344, 5440)
  k_plstm_asm<<<16384 + 4096, 256, 0, stream>>>(
      16384, GATESP, WIHPT, BP, CP[1], feat, HP[0], CP[0], 8, 85,
      1344, PPA, UPROJ[0], UPROJ[1], UPROJ[2], HPRED);
  // L13: pdual5 (256, PPA only, ny=2)
  k_gemm<<<256, 256, 0, stream>>>(HP[0], UPWHHP, 16384, 128, MODE_PPA,
                                  PPA, 5440, nullptr, nullptr, nullptr);
  // L14: assemble rows [5440, 21824)
  k_assemble<<<16384, 256, 0, stream>>>(5440, PPA, UPROJ[0], UPROJ[1],
                                        UPROJ[2], HPRED);
  // L15: fused tail (GEMM + log-softmax, HPRED reader, 512-thread blocks)
  k_mm_tail<<<2730, 512, 0, stream>>>(HPRED, WEXT, BE, out);

  (void)in_sizes; (void)n_in; (void)out_size; (void)ws_size;
}